// Round 17
// baseline (337.626 us; speedup 1.0000x reference)
//
#include <hip/hip_runtime.h>
#include <hip/hip_bf16.h>
#include <hip/hip_cooperative_groups.h>
#include <math.h>

namespace cg = cooperative_groups;

#define BB 4
#define HH 8
#define PP 32
#define NN 32
#define DD 16
#define LL 1024      // PP*NN
#define WINW 10
#define NFF 6
#define PREDL 96
#define SEQL 512
#define EPSF 1.1920928955078125e-07f
#define KROW 24      // shorts per staged key row (48 B, 16B-aligned)
#define KTS 296      // shorts per VT row (288 keys + 8 pad)
#define PROW 40      // shorts per P row (80 B, 16B-aligned)
#define XROW 20      // floats per xls row (80 B, 16B-aligned)

typedef __attribute__((ext_vector_type(8))) short bf16x8;
typedef __attribute__((ext_vector_type(4))) float f32x4;

__device__ inline short f2bs(float f) {
    __hip_bfloat16 h = __float2bfloat16(f);
    return *reinterpret_cast<short*>(&h);
}

// ---- single shared-memory arena, declared ONCE and reused by both layers ----
struct __align__(16) LayerSmem {
    short hK[9 * 32 * KROW];   // 13824 B keys row-major (bf16)
    short VT[16 * KTS];        //  9472 B keys dim-major
    short Pp[2][16 * PROW];    //  2560 B (per-wave)
    short Pn[2][16 * PROW];    //  2560 B
    float xls[32 * XROW];      //  2560 B
};                             // total 30976 B -> 5 blocks/CU -> 1280 >= 1024 OK

// ---- r14 layer body (2 waves per (b,h,patch) task) ----
__device__ __forceinline__ void do_layer(
    LayerSmem* sm,
    const float* __restrict__ hin, float* __restrict__ hout,
    const float* __restrict__ log_scales, const float* __restrict__ attn_norm,
    const float* __restrict__ up_w, const float* __restrict__ down_w,
    const float* __restrict__ ffn_norm, int layer)
{
    int blk = blockIdx.x;
    int bh  = blk >> 5;            // (b*8+h)
    int hh  = bh & 7;
    int p0  = blk & 31;
    int nstage = min(9, (PP - 1) - p0);

    int tid  = threadIdx.x;
    int wid  = tid >> 6;           // wave id: query half
    int lane = tid & 63;
    int quad = lane >> 4, n16 = lane & 15;

    // ---- stage keys: fp32 -> bf16, row-major + transposed ----
    {
        const float4* src = (const float4*)(hin + ((size_t)bh * LL + (p0 + 1) * NN) * DD);
        if (nstage == 9) {
            #pragma unroll
            for (int k = 0; k < 9; ++k) {
                int i = tid + k * 128;                 // 1152 = 9*128 exactly
                int row = i >> 2, j = i & 3;
                float4 v = src[i];
                short s0 = f2bs(v.x), s1 = f2bs(v.y), s2 = f2bs(v.z), s3 = f2bs(v.w);
                unsigned long long u =
                      (unsigned long long)(unsigned short)s0
                    | ((unsigned long long)(unsigned short)s1 << 16)
                    | ((unsigned long long)(unsigned short)s2 << 32)
                    | ((unsigned long long)(unsigned short)s3 << 48);
                *(unsigned long long*)&sm->hK[row * KROW + j * 4] = u;
                int d0 = j * 4;
                sm->VT[(d0 + 0) * KTS + row] = s0;
                sm->VT[(d0 + 1) * KTS + row] = s1;
                sm->VT[(d0 + 2) * KTS + row] = s2;
                sm->VT[(d0 + 3) * KTS + row] = s3;
            }
        } else {
            int nf4 = nstage * 128;
            for (int i = tid; i < nf4; i += 128) {
                int row = i >> 2, j = i & 3;
                float4 v = src[i];
                short s0 = f2bs(v.x), s1 = f2bs(v.y), s2 = f2bs(v.z), s3 = f2bs(v.w);
                unsigned long long u =
                      (unsigned long long)(unsigned short)s0
                    | ((unsigned long long)(unsigned short)s1 << 16)
                    | ((unsigned long long)(unsigned short)s2 << 32)
                    | ((unsigned long long)(unsigned short)s3 << 48);
                *(unsigned long long*)&sm->hK[row * KROW + j * 4] = u;
                int d0 = j * 4;
                sm->VT[(d0 + 0) * KTS + row] = s0;
                sm->VT[(d0 + 1) * KTS + row] = s1;
                sm->VT[(d0 + 2) * KTS + row] = s2;
                sm->VT[(d0 + 3) * KTS + row] = s3;
            }
        }
    }

    // ---- preload Q A-frag and residual (global; overlaps staging) ----
    bf16x8 Aq;
    #pragma unroll
    for (int j = 0; j < 8; ++j) Aq[j] = 0;
    if (quad < 2) {
        const float* qp = hin + ((size_t)bh * LL + p0 * NN + wid * 16 + n16) * DD + quad * 8;
        #pragma unroll
        for (int j = 0; j < 8; ++j) Aq[j] = f2bs(qp[j]);
    }
    float rs[4];
    #pragma unroll
    for (int r = 0; r < 4; ++r)
        rs[r] = hin[((size_t)bh * LL + p0 * NN + wid * 16 + quad * 4 + r) * DD + n16];

    float sc = fminf(fmaxf(__expf(log_scales[layer]), 1.0f), 30.0f) * 0.25f;

    __syncthreads();   // staging done

    // ---- chunk loop: one key patch per chunk, no barriers ----
    f32x4 Op, On;
    Op[0] = Op[1] = Op[2] = Op[3] = 0.f;
    On[0] = On[1] = On[2] = On[3] = 0.f;
    float lpp[4] = {0.f, 0.f, 0.f, 0.f}, lnn[4] = {0.f, 0.f, 0.f, 0.f};
    short* myPp = sm->Pp[wid];
    short* myPn = sm->Pn[wid];

    for (int c = 0; c < nstage; ++c) {
        int kb = c * 32;
        #pragma unroll
        for (int kt = 0; kt < 2; ++kt) {
            bf16x8 Bk;
            #pragma unroll
            for (int j = 0; j < 8; ++j) Bk[j] = 0;
            if (quad < 2)
                Bk = *(const bf16x8*)&sm->hK[(kb + kt * 16 + n16) * KROW + quad * 8];
            f32x4 z; z[0] = z[1] = z[2] = z[3] = 0.f;
            f32x4 S = __builtin_amdgcn_mfma_f32_16x16x32_bf16(Aq, Bk, z, 0, 0, 0);
            #pragma unroll
            for (int r = 0; r < 4; ++r) {
                float s  = S[r];
                float ep = __expf(sc * s);
                float en = __expf(-sc * s);
                lpp[r] += ep; lnn[r] += en;
                int pr = quad * 4 + r, pc = kt * 16 + n16;
                myPp[pr * PROW + pc] = f2bs(ep);
                myPn[pr * PROW + pc] = f2bs(en);
            }
        }
        // PV: contiguous b128 frags (same-wave LDS ordering via lgkmcnt)
        bf16x8 Bv = *(const bf16x8*)&sm->VT[n16 * KTS + kb + quad * 8];
        bf16x8 Ap = *(const bf16x8*)&myPp[n16 * PROW + quad * 8];
        bf16x8 An = *(const bf16x8*)&myPn[n16 * PROW + quad * 8];
        Op = __builtin_amdgcn_mfma_f32_16x16x32_bf16(Ap, Bv, Op, 0, 0, 0);
        On = __builtin_amdgcn_mfma_f32_16x16x32_bf16(An, Bv, On, 0, 0, 0);
    }

    // ---- reduce lp/ln over the 16 key-columns ----
    #pragma unroll
    for (int r = 0; r < 4; ++r) {
        float a = lpp[r], b = lnn[r];
        a += __shfl_xor(a, 1); a += __shfl_xor(a, 2); a += __shfl_xor(a, 4); a += __shfl_xor(a, 8);
        b += __shfl_xor(b, 1); b += __shfl_xor(b, 2); b += __shfl_xor(b, 4); b += __shfl_xor(b, 8);
        lpp[r] = a; lnn[r] = b;
    }

    // ---- residual + attn RMSNorm (C-layout), stash rows to xls ----
    #pragma unroll
    for (int r = 0; r < 4; ++r) {
        float lp = lpp[r], ln = lnn[r];
        float rl = (lp > 0.f) ? (1.0f / lp) : 0.f;
        float rn = (ln > 0.f) ? (1.0f / ln) : 0.f;
        float v  = rs[r] + Op[r] * rl - On[r] * rn;
        float ss = v * v;
        ss += __shfl_xor(ss, 1); ss += __shfl_xor(ss, 2);
        ss += __shfl_xor(ss, 4); ss += __shfl_xor(ss, 8);
        float rr = rsqrtf(ss * (1.0f / 16.0f) + EPSF);
        sm->xls[(wid * 16 + quad * 4 + r) * XROW + n16] = v * rr * attn_norm[layer * DD + n16];
    }
    // each wave reads only rows it wrote -> no barrier needed

    // ---- conv-FFN + residual + RMSNorm: 16 lanes per wave, one query each ----
    if (lane < 16) {
        int q = wid * 16 + lane;
        float x[16];
        #pragma unroll
        for (int j = 0; j < 4; ++j) {
            float4 v = *(const float4*)&sm->xls[q * XROW + j * 4];
            x[j*4+0] = v.x; x[j*4+1] = v.y; x[j*4+2] = v.z; x[j*4+3] = v.w;
        }

        const float* uw = up_w + (size_t)(layer * 2 * HH + 2 * hh) * 3;
        float w00 = uw[0], w01 = uw[1], w02 = uw[2];
        float w10 = uw[3], w11 = uw[4], w12 = uw[5];
        const float* dw = down_w + (size_t)(layer * HH + hh) * 2;
        float dc0 = dw[0], dc1 = dw[1];

        float v[16], ss = 0.f;
        #pragma unroll
        for (int i = 0; i < 16; ++i) {
            float xm2 = (i >= 2) ? x[i - 2] : 0.f;
            float xm1 = (i >= 1) ? x[i - 1] : 0.f;
            float u0 = w00 * xm2 + w01 * xm1 + w02 * x[i];
            float u1 = w10 * xm2 + w11 * xm1 + w12 * x[i];
            float g0 = 0.5f * u0 * (1.0f + erff(u0 * 0.7071067811865475f));
            float g1 = 0.5f * u1 * (1.0f + erff(u1 * 0.7071067811865475f));
            float vv = x[i] + dc0 * g0 + dc1 * g1;
            v[i] = vv; ss += vv * vv;
        }
        float r2 = rsqrtf(ss * (1.0f / 16.0f) + EPSF);
        float* op = hout + ((size_t)bh * LL + p0 * NN + q) * DD;
        #pragma unroll
        for (int i = 0; i < 16; ++i) op[i] = v[i] * r2 * ffn_norm[layer * DD + i];
    }
}

// ---- tail work (shared by mega kernel and fallback tail kernel) ----
__device__ __forceinline__ void do_tail(
    int t, const float* __restrict__ h, const float* __restrict__ mw_,
    const float* __restrict__ mb_, const float* __restrict__ fw_,
    const float* __restrict__ fb_, const float* __restrict__ x,
    float* __restrict__ out)
{
    if (t < BB * DD * NFF * NN) {
        int n = t & 31;
        int r = t >> 5;
        int fi = r % NFF; r /= NFF;
        int d = r & 15;
        int b = r >> 4;

        float mw[8];
        #pragma unroll
        for (int k = 0; k < 8; ++k) mw[k] = mw_[k];
        float mb = mb_[0];

        float acc = fb_[fi];
        for (int p = 0; p < PP; ++p) {
            float m = mb;
            #pragma unroll
            for (int k = 0; k < 8; ++k)
                m += h[(size_t)(((b * HH + k) * LL) + p * NN + n) * DD + d] * mw[k];
            acc += m * fw_[fi * PP + p];
        }
        out[t] = acc;   // flat index == t: b*3072 + (d*6+fi)*32 + n
    } else {
        int u4 = t - BB * DD * NFF * NN;
        if (u4 < BB * SEQL * NN / 4) {
            const float4* x4 = (const float4*)x;
            float4* o4 = (float4*)(out + BB * PREDL * NN);
            o4[u4] = x4[u4];
        }
    }
}

// ======= cooperative: layer0 -> grid.sync -> layer1 -> grid.sync -> tail ===
__global__ __launch_bounds__(128) void mega_kernel(
    const float* __restrict__ tokens, float* __restrict__ hA, float* __restrict__ hB,
    const float* __restrict__ log_scales, const float* __restrict__ attn_norm,
    const float* __restrict__ up_w, const float* __restrict__ down_w,
    const float* __restrict__ ffn_norm, const float* __restrict__ mw_,
    const float* __restrict__ mb_, const float* __restrict__ fw_,
    const float* __restrict__ fb_, const float* __restrict__ x,
    float* __restrict__ out)
{
    __shared__ LayerSmem sm;     // ONE arena reused by both layers (30.25 KB)
    cg::grid_group grid = cg::this_grid();

    do_layer(&sm, tokens, hA, log_scales, attn_norm, up_w, down_w, ffn_norm, 0);
    grid.sync();
    do_layer(&sm, hA, hB, log_scales, attn_norm, up_w, down_w, ffn_norm, 1);
    grid.sync();

    do_tail(blockIdx.x * 128 + threadIdx.x, hB, mw_, mb_, fw_, fb_, x, out);
}

// ======= fallback (r14 path): standalone layer + tail kernels ===============
__global__ __launch_bounds__(128) void layer_kernel(
    const float* __restrict__ hin, float* __restrict__ hout,
    const float* __restrict__ log_scales, const float* __restrict__ attn_norm,
    const float* __restrict__ up_w, const float* __restrict__ down_w,
    const float* __restrict__ ffn_norm, int layer)
{
    __shared__ LayerSmem sm;
    do_layer(&sm, hin, hout, log_scales, attn_norm, up_w, down_w, ffn_norm, layer);
}

__global__ void tail_kernel(const float* __restrict__ h, const float* __restrict__ mw_,
                            const float* __restrict__ mb_, const float* __restrict__ fw_,
                            const float* __restrict__ fb_, const float* __restrict__ x,
                            float* __restrict__ out)
{
    do_tail(blockIdx.x * 256 + threadIdx.x, h, mw_, mb_, fw_, fb_, x, out);
}

// ---------------- host-side input identification by element count ----------------
static int find_by_size(const int* s, int n, int want, int occurrence) {
    int seen = 0;
    for (int i = 0; i < n; ++i)
        if (s[i] == want) { if (seen == occurrence) return i; ++seen; }
    return -1;
}

extern "C" void kernel_launch(void* const* d_in, const int* in_sizes, int n_in,
                              void* d_out, int out_size, void* d_ws, size_t ws_size,
                              hipStream_t stream) {
    int it  = find_by_size(in_sizes, n_in, 524288, 0);
    int ix  = find_by_size(in_sizes, n_in, 65536, 0);
    int ils = find_by_size(in_sizes, n_in, 2, 0);
    int ian = find_by_size(in_sizes, n_in, 32, 0);   // attn_norm_w (1st 32)
    int icu = find_by_size(in_sizes, n_in, 96, 0);
    int icd = find_by_size(in_sizes, n_in, 32, 1);   // conv_down_w (2nd 32)
    int ifn = find_by_size(in_sizes, n_in, 32, 2);   // ffn_norm_w  (3rd 32)
    int imw = find_by_size(in_sizes, n_in, 8, 0);
    int imb = find_by_size(in_sizes, n_in, 1, 0);
    int ifw = find_by_size(in_sizes, n_in, 192, 0);
    int ifb = find_by_size(in_sizes, n_in, 6, 0);
    if (it < 0 || ix < 0 || ils < 0 || ian < 0 || icu < 0 || icd < 0 ||
        ifn < 0 || imw < 0 || imb < 0 || ifw < 0 || ifb < 0) {
        it = 0; ix = 1; ils = 2; ian = 3; icu = 4; icd = 5; ifn = 6;
        imw = 7; imb = 8; ifw = 9; ifb = 10;
    }

    const float* tokens     = (const float*)d_in[it];
    const float* x_orig     = (const float*)d_in[ix];
    const float* log_scales = (const float*)d_in[ils];
    const float* attn_norm  = (const float*)d_in[ian];
    const float* up_w       = (const float*)d_in[icu];
    const float* down_w     = (const float*)d_in[icd];
    const float* ffn_norm   = (const float*)d_in[ifn];
    const float* mix_w      = (const float*)d_in[imw];
    const float* mix_b      = (const float*)d_in[imb];
    const float* fore_w     = (const float*)d_in[ifw];
    const float* fore_b     = (const float*)d_in[ifb];
    float* out = (float*)d_out;          // fp32 output (verified round 7)

    const size_t NH = (size_t)BB * HH * LL * DD;
    float* hA = (float*)d_ws;        // 2 MB
    float* hB = hA + NH;             // 2 MB

    void* args[] = {
        (void*)&tokens, (void*)&hA, (void*)&hB, (void*)&log_scales,
        (void*)&attn_norm, (void*)&up_w, (void*)&down_w, (void*)&ffn_norm,
        (void*)&mix_w, (void*)&mix_b, (void*)&fore_w, (void*)&fore_b,
        (void*)&x_orig, (void*)&out
    };
    hipError_t err = hipLaunchCooperativeKernel((void*)mega_kernel, dim3(1024),
                                                dim3(128), args, 0, stream);
    if (err != hipSuccess) {
        (void)hipGetLastError();   // clear error state, take the r14 path
        layer_kernel<<<1024, 128, 0, stream>>>(tokens, hA, log_scales, attn_norm,
                                               up_w, down_w, ffn_norm, 0);
        layer_kernel<<<1024, 128, 0, stream>>>(hA, hB, log_scales, attn_norm,
                                               up_w, down_w, ffn_norm, 1);
        const int tail_threads = BB * DD * NFF * NN + BB * SEQL * NN / 4;
        tail_kernel<<<(tail_threads + 255) / 256, 256, 0, stream>>>(
            hB, mix_w, mix_b, fore_w, fore_b, x_orig, out);
    }
}

// Round 18
// 134.918 us; speedup vs baseline: 2.5025x; 2.5025x over previous
//
#include <hip/hip_runtime.h>
#include <hip/hip_bf16.h>
#include <math.h>

#define BB 4
#define HH 8
#define PP 32
#define NN 32
#define DD 16
#define LL 1024      // PP*NN
#define WINW 10
#define NFF 6
#define PREDL 96
#define SEQL 512
#define EPSF 1.1920928955078125e-07f
#define PROW 40      // shorts per P row (80 B, 16B-aligned)
#define XROW 20      // floats per xls row (80 B, 16B-aligned)

typedef __attribute__((ext_vector_type(8))) short bf16x8;
typedef __attribute__((ext_vector_type(4))) float f32x4;

__device__ inline short f2bs(float f) {
    __hip_bfloat16 h = __float2bfloat16(f);
    return *reinterpret_cast<short*>(&h);
}

// ======= MFMA fused layer, NO global->LDS staging =======
// Grid: 1024 blocks x 128 (2 independent waves per (b,h,patch); wave = query half).
// QK^T B-frag: 2xfloat4 straight from global (L1-hot: rows shared by 10 nearby
// blocks and both waves). PV B-frag: 8 column-strided global floats per lane,
// issued at chunk top, hidden under S/exp. P round-trips through wave-private
// LDS (same-wave ordering via lgkmcnt). ZERO barriers. exp in fp32, no max-sub
// (validated r9-r16). LDS 7.7 KB/block.
__global__ __launch_bounds__(128) void layer_kernel(
    const float* __restrict__ hin, float* __restrict__ hout,
    const float* __restrict__ log_scales, const float* __restrict__ attn_norm,
    const float* __restrict__ up_w, const float* __restrict__ down_w,
    const float* __restrict__ ffn_norm, int layer)
{
    __shared__ short Pp[2][16 * PROW];    // 2.5 KB (per-wave)
    __shared__ short Pn[2][16 * PROW];    // 2.5 KB
    __shared__ float xls[32 * XROW];      // 2.5 KB

    int blk = blockIdx.x;
    int bh  = blk >> 5;            // (b*8+h)
    int hh  = bh & 7;
    int p0  = blk & 31;
    int nstage = min(9, (PP - 1) - p0);

    int tid  = threadIdx.x;
    int wid  = tid >> 6;           // wave id: query half
    int lane = tid & 63;
    int quad = lane >> 4, n16 = lane & 15;

    const float* hbase = hin + (size_t)bh * LL * DD;
    const float* kglob = hbase + (size_t)(p0 + 1) * NN * DD;   // key block base

    // ---- Q A-frag and residual from global ----
    bf16x8 Aq;
    #pragma unroll
    for (int j = 0; j < 8; ++j) Aq[j] = 0;
    if (quad < 2) {
        const float* qp = hbase + (size_t)(p0 * NN + wid * 16 + n16) * DD + quad * 8;
        #pragma unroll
        for (int j = 0; j < 8; ++j) Aq[j] = f2bs(qp[j]);
    }
    float rs[4];
    #pragma unroll
    for (int r = 0; r < 4; ++r)
        rs[r] = hbase[(size_t)(p0 * NN + wid * 16 + quad * 4 + r) * DD + n16];

    float sc = fminf(fmaxf(__expf(log_scales[layer]), 1.0f), 30.0f) * 0.25f;

    // ---- chunk loop: one key patch (32 keys) per chunk, no barriers ----
    f32x4 Op, On;
    Op[0] = Op[1] = Op[2] = Op[3] = 0.f;
    On[0] = On[1] = On[2] = On[3] = 0.f;
    float lpp[4] = {0.f, 0.f, 0.f, 0.f}, lnn[4] = {0.f, 0.f, 0.f, 0.f};
    short* myPp = Pp[wid];
    short* myPn = Pn[wid];

    for (int c = 0; c < nstage; ++c) {
        int kb = c * 32;

        // PV B-frag: V[kb+quad*8+j][n16] — issue early, consumed after S/exp
        bf16x8 Bvc;
        {
            const float* vp = kglob + (size_t)(kb + quad * 8) * DD + n16;
            #pragma unroll
            for (int j = 0; j < 8; ++j) Bvc[j] = f2bs(vp[j * DD]);
        }

        #pragma unroll
        for (int kt = 0; kt < 2; ++kt) {
            bf16x8 Bk;
            #pragma unroll
            for (int j = 0; j < 8; ++j) Bk[j] = 0;
            if (quad < 2) {
                const float* kp = kglob + (size_t)(kb + kt * 16 + n16) * DD + quad * 8;
                float4 v0 = *(const float4*)kp;
                float4 v1 = *(const float4*)(kp + 4);
                Bk[0] = f2bs(v0.x); Bk[1] = f2bs(v0.y); Bk[2] = f2bs(v0.z); Bk[3] = f2bs(v0.w);
                Bk[4] = f2bs(v1.x); Bk[5] = f2bs(v1.y); Bk[6] = f2bs(v1.z); Bk[7] = f2bs(v1.w);
            }
            f32x4 z; z[0] = z[1] = z[2] = z[3] = 0.f;
            f32x4 S = __builtin_amdgcn_mfma_f32_16x16x32_bf16(Aq, Bk, z, 0, 0, 0);
            #pragma unroll
            for (int r = 0; r < 4; ++r) {
                float s  = S[r];
                float ep = __expf(sc * s);
                float en = __expf(-sc * s);
                lpp[r] += ep; lnn[r] += en;
                int pr = quad * 4 + r, pc = kt * 16 + n16;   // row=query, col=key
                myPp[pr * PROW + pc] = f2bs(ep);
                myPn[pr * PROW + pc] = f2bs(en);
            }
        }
        // PV: A[m=n16 query][k=quad*8+j key] from wave-private LDS
        bf16x8 Ap = *(const bf16x8*)&myPp[n16 * PROW + quad * 8];
        bf16x8 An = *(const bf16x8*)&myPn[n16 * PROW + quad * 8];
        Op = __builtin_amdgcn_mfma_f32_16x16x32_bf16(Ap, Bvc, Op, 0, 0, 0);
        On = __builtin_amdgcn_mfma_f32_16x16x32_bf16(An, Bvc, On, 0, 0, 0);
    }

    // ---- reduce lp/ln over the 16 key-columns ----
    #pragma unroll
    for (int r = 0; r < 4; ++r) {
        float a = lpp[r], b = lnn[r];
        a += __shfl_xor(a, 1); a += __shfl_xor(a, 2); a += __shfl_xor(a, 4); a += __shfl_xor(a, 8);
        b += __shfl_xor(b, 1); b += __shfl_xor(b, 2); b += __shfl_xor(b, 4); b += __shfl_xor(b, 8);
        lpp[r] = a; lnn[r] = b;
    }

    // ---- residual + attn RMSNorm (C-layout), stash rows to xls ----
    #pragma unroll
    for (int r = 0; r < 4; ++r) {
        float lp = lpp[r], ln = lnn[r];
        float rl = (lp > 0.f) ? (1.0f / lp) : 0.f;
        float rn = (ln > 0.f) ? (1.0f / ln) : 0.f;
        float v  = rs[r] + Op[r] * rl - On[r] * rn;
        float ss = v * v;
        ss += __shfl_xor(ss, 1); ss += __shfl_xor(ss, 2);
        ss += __shfl_xor(ss, 4); ss += __shfl_xor(ss, 8);
        float rr = rsqrtf(ss * (1.0f / 16.0f) + EPSF);
        xls[(wid * 16 + quad * 4 + r) * XROW + n16] = v * rr * attn_norm[layer * DD + n16];
    }
    // each wave reads only rows it wrote -> no barrier needed

    // ---- conv-FFN + residual + RMSNorm: 16 lanes per wave, one query each ----
    if (lane < 16) {
        int q = wid * 16 + lane;
        float x[16];
        #pragma unroll
        for (int j = 0; j < 4; ++j) {
            float4 v = *(const float4*)&xls[q * XROW + j * 4];
            x[j*4+0] = v.x; x[j*4+1] = v.y; x[j*4+2] = v.z; x[j*4+3] = v.w;
        }

        const float* uw = up_w + (size_t)(layer * 2 * HH + 2 * hh) * 3;
        float w00 = uw[0], w01 = uw[1], w02 = uw[2];
        float w10 = uw[3], w11 = uw[4], w12 = uw[5];
        const float* dw = down_w + (size_t)(layer * HH + hh) * 2;
        float dc0 = dw[0], dc1 = dw[1];

        float v[16], ss = 0.f;
        #pragma unroll
        for (int i = 0; i < 16; ++i) {
            float xm2 = (i >= 2) ? x[i - 2] : 0.f;
            float xm1 = (i >= 1) ? x[i - 1] : 0.f;
            float u0 = w00 * xm2 + w01 * xm1 + w02 * x[i];
            float u1 = w10 * xm2 + w11 * xm1 + w12 * x[i];
            float g0 = 0.5f * u0 * (1.0f + erff(u0 * 0.7071067811865475f));
            float g1 = 0.5f * u1 * (1.0f + erff(u1 * 0.7071067811865475f));
            float vv = x[i] + dc0 * g0 + dc1 * g1;
            v[i] = vv; ss += vv * vv;
        }
        float r2 = rsqrtf(ss * (1.0f / 16.0f) + EPSF);
        float* op = hout + ((size_t)bh * LL + p0 * NN + q) * DD;
        #pragma unroll
        for (int i = 0; i < 16; ++i) op[i] = v[i] * r2 * ffn_norm[layer * DD + i];
    }
}

// ---------------- tail: head-mix + forecast projection, and x passthrough ----
__global__ void tail_kernel(const float* __restrict__ h, const float* __restrict__ mw_,
                            const float* __restrict__ mb_, const float* __restrict__ fw_,
                            const float* __restrict__ fb_, const float* __restrict__ x,
                            float* __restrict__ out)
{
    int t = blockIdx.x * 256 + threadIdx.x;
    if (t < BB * DD * NFF * NN) {
        int n = t & 31;
        int r = t >> 5;
        int fi = r % NFF; r /= NFF;
        int d = r & 15;
        int b = r >> 4;

        float mw[8];
        #pragma unroll
        for (int k = 0; k < 8; ++k) mw[k] = mw_[k];
        float mb = mb_[0];

        float acc = fb_[fi];
        for (int p = 0; p < PP; ++p) {
            float m = mb;
            #pragma unroll
            for (int k = 0; k < 8; ++k)
                m += h[(size_t)(((b * HH + k) * LL) + p * NN + n) * DD + d] * mw[k];
            acc += m * fw_[fi * PP + p];
        }
        out[t] = acc;   // flat index == t: b*3072 + (d*6+fi)*32 + n
    } else {
        int u4 = t - BB * DD * NFF * NN;           // float4 index into x
        if (u4 < BB * SEQL * NN / 4) {
            const float4* x4 = (const float4*)x;
            float4* o4 = (float4*)(out + BB * PREDL * NN);
            o4[u4] = x4[u4];
        }
    }
}

// ---------------- host-side input identification by element count ----------------
static int find_by_size(const int* s, int n, int want, int occurrence) {
    int seen = 0;
    for (int i = 0; i < n; ++i)
        if (s[i] == want) { if (seen == occurrence) return i; ++seen; }
    return -1;
}

extern "C" void kernel_launch(void* const* d_in, const int* in_sizes, int n_in,
                              void* d_out, int out_size, void* d_ws, size_t ws_size,
                              hipStream_t stream) {
    int it  = find_by_size(in_sizes, n_in, 524288, 0);
    int ix  = find_by_size(in_sizes, n_in, 65536, 0);
    int ils = find_by_size(in_sizes, n_in, 2, 0);
    int ian = find_by_size(in_sizes, n_in, 32, 0);   // attn_norm_w (1st 32)
    int icu = find_by_size(in_sizes, n_in, 96, 0);
    int icd = find_by_size(in_sizes, n_in, 32, 1);   // conv_down_w (2nd 32)
    int ifn = find_by_size(in_sizes, n_in, 32, 2);   // ffn_norm_w  (3rd 32)
    int imw = find_by_size(in_sizes, n_in, 8, 0);
    int imb = find_by_size(in_sizes, n_in, 1, 0);
    int ifw = find_by_size(in_sizes, n_in, 192, 0);
    int ifb = find_by_size(in_sizes, n_in, 6, 0);
    if (it < 0 || ix < 0 || ils < 0 || ian < 0 || icu < 0 || icd < 0 ||
        ifn < 0 || imw < 0 || imb < 0 || ifw < 0 || ifb < 0) {
        it = 0; ix = 1; ils = 2; ian = 3; icu = 4; icd = 5; ifn = 6;
        imw = 7; imb = 8; ifw = 9; ifb = 10;
    }

    const float* tokens     = (const float*)d_in[it];
    const float* x_orig     = (const float*)d_in[ix];
    const float* log_scales = (const float*)d_in[ils];
    const float* attn_norm  = (const float*)d_in[ian];
    const float* up_w       = (const float*)d_in[icu];
    const float* down_w     = (const float*)d_in[icd];
    const float* ffn_norm   = (const float*)d_in[ifn];
    const float* mix_w      = (const float*)d_in[imw];
    const float* mix_b      = (const float*)d_in[imb];
    const float* fore_w     = (const float*)d_in[ifw];
    const float* fore_b     = (const float*)d_in[ifb];
    float* out = (float*)d_out;          // fp32 output (verified round 7)

    const size_t NH = (size_t)BB * HH * LL * DD;
    float* hA = (float*)d_ws;        // 2 MB
    float* hB = hA + NH;             // 2 MB

    layer_kernel<<<1024, 128, 0, stream>>>(tokens, hA, log_scales, attn_norm,
                                           up_w, down_w, ffn_norm, 0);
    layer_kernel<<<1024, 128, 0, stream>>>(hA, hB, log_scales, attn_norm,
                                           up_w, down_w, ffn_norm, 1);
    const int tail_threads = BB * DD * NFF * NN + BB * SEQL * NN / 4;  // 12288 + 16384
    tail_kernel<<<(tail_threads + 255) / 256, 256, 0, stream>>>(
        hB, mix_w, mix_b, fore_w, fore_b, x_orig, out);
}